// Round 6
// baseline (32778.995 us; speedup 1.0000x reference)
//
#include <hip/hip_runtime.h>
#include <hip/hip_bf16.h>

// LSTM_19267223290530 — 2-layer LSTM (B=64,T=1024,IN=128,HID=512) + FC.
// Round 6: FUSED both layers in one persistent launch, two interleaved
// batch-chains per wg. 256 wgs = 2 layers x 2 supersets x 64 wgs; each wg
// owns 8 hidden units for two 16-batch chains (shared LDS weights).
// Chain A's barrier/load latency hides under chain B's compute and vice
// versa; L1 consumes L0's seq output with ~1-step lag (L0 never waits).
// Serial span: ~1024 ticks instead of 2048 steps.

#define NTH 256
#define BPG 16
#define HIDDEN 512
#define TSTEPS 1024
#define BATCH 64

// spin bail-out (~4 s in s_memrealtime ticks): fail visibly, never hang.
#define SPIN_LIMIT 400000000ull

using bf16 = __hip_bfloat16;

__device__ __forceinline__ float b2fl(unsigned short s) {
  return __uint_as_float(((unsigned int)s) << 16);
}
__device__ __forceinline__ float sigm(float x) { return 1.0f / (1.0f + __expf(-x)); }
__device__ __forceinline__ float tanh_fast(float x) {
  float ax = fabsf(x);
  float e2 = __expf(2.0f * ax);
  float t  = 1.0f - 2.0f / (e2 + 1.0f);
  return copysignf(t, x);
}
__device__ __forceinline__ void fma4(float& a, const float4 w, const float4 h) {
  a = fmaf(w.x, h.x, a);
  a = fmaf(w.y, h.y, a);
  a = fmaf(w.z, h.z, a);
  a = fmaf(w.w, h.w, a);
}

// relaxed agent-scope (device-coherent, no cache-maintenance) ops
__device__ __forceinline__ void st_cc(float* p, float v) {
  __hip_atomic_store(p, v, __ATOMIC_RELAXED, __HIP_MEMORY_SCOPE_AGENT);
}
__device__ __forceinline__ float ld_cc(const float* p) {
  return __hip_atomic_load((float*)p, __ATOMIC_RELAXED, __HIP_MEMORY_SCOPE_AGENT);
}
__device__ __forceinline__ void st_cu(unsigned* p, unsigned v) {
  __hip_atomic_store(p, v, __ATOMIC_RELAXED, __HIP_MEMORY_SCOPE_AGENT);
}
__device__ __forceinline__ unsigned ld_cu(const unsigned* p) {
  return __hip_atomic_load((unsigned*)p, __ATOMIC_RELAXED, __HIP_MEMORY_SCOPE_AGENT);
}
__device__ __forceinline__ void st_ci(int* p, int v) {
  __hip_atomic_store(p, v, __ATOMIC_RELAXED, __HIP_MEMORY_SCOPE_AGENT);
}
__device__ __forceinline__ int ld_ci(const int* p) {
  return __hip_atomic_load((int*)p, __ATOMIC_RELAXED, __HIP_MEMORY_SCOPE_AGENT);
}
__device__ __forceinline__ void cfence() { asm volatile("" ::: "memory"); }

// ---------------------------------------------------------------------------
// Fused persistent scan. grid = 256 wgs x 256 thr (1 wg/CU).
//   bid>>7 = layer, (bid>>6)&1 = superset s, bid&63 = w (unit slice u0=8w).
//   chains cA=2s, cB=2s+1 cover batches [16c,16c+16).
// Per tick t: phase A (step t of chain A) with {wait/issue B} sandwiched
// between x-part and h-part; then phase B with {wait/issue A(t+1)}.
// LDS: w_hh [32][128]f4 swz (64K) + w_ih0 [32][32]f4 (16K, L0) +
//      2 x 32K shared x/h stage (reduction overlays stage) + bias/c-state.
// SEQMODE 0: f32 seq (st_cc float), 1: packed 2xbf16 per u32.
// ---------------------------------------------------------------------------
template<int SEQMODE>
__global__ __launch_bounds__(NTH, 1)
void lstm_fused(const float* __restrict__ xin,
                const float* __restrict__ wih0, const float* __restrict__ whh0,
                const float* __restrict__ bih0, const float* __restrict__ bhh0,
                const float* __restrict__ wih1, const float* __restrict__ whh1,
                const float* __restrict__ bih1, const float* __restrict__ bhh1,
                float* __restrict__ hbufs,      // [2L][4c][2][16][512]
                void* __restrict__ seqv,        // f32 [64][1024][512] | u32 [64][1024][256]
                float* __restrict__ fin,        // [64][512] final h2
                int* __restrict__ bars)         // flags [8][64] @0; epochs @512+c16*16
{
  const int tid = threadIdx.x;
  const int bid = blockIdx.x;
  const int L   = bid >> 7;
  const int s   = (bid >> 6) & 1;
  const int w   = bid & 63;
  const int u0  = w * 8;

  const float* w_ih = L ? wih1 : wih0;
  const float* w_hh = L ? whh1 : whh0;
  const float* b_ih = L ? bih1 : bih0;
  const float* b_hh = L ? bhh1 : bhh0;

  float*    seqf = (float*)seqv;
  unsigned* sequ = (unsigned*)seqv;

  extern __shared__ float lds[];
  float4* wv4  = (float4*)lds;            // [32][128] w_hh slice, swizzled
  float4* wx4  = wv4 + 32 * 128;          // [32][32] w_ih0 slice (L0 only)
  float*  st0  = (float*)(wx4 + 32 * 32); // chain A stage (16*512 f)
  float*  st1  = st0 + BPG * HIDDEN;      // chain B stage
  float*  bsum = st1 + BPG * HIDDEN;      // [32]
  float*  cst  = bsum + 32;               // [2][128] c-state
  float*  stf[2] = { st0, st1 };

  float* hbc[2]; int* fl[2]; int* ep[2]; int* ep0[2]; int b0c[2];
#pragma unroll
  for (int ci = 0; ci < 2; ++ci) {
    const int c = 2 * s + ci;
    hbc[ci] = hbufs + (size_t)((L * 4 + c) * 2) * (BPG * HIDDEN);
    fl[ci]  = bars + (L * 4 + c) * 64;
    ep[ci]  = bars + 512 + (L * 4 + c) * 16;
    ep0[ci] = bars + 512 + c * 16;           // layer-0 epoch, same chain id
    b0c[ci] = c * BPG;
  }

  // ---- weights -> LDS ----
  for (int idx = tid; idx < 32 * 128; idx += NTH) {
    int r = idx >> 7, c4 = idx & 127, swz = (r >> 2) & 7;
    int grow = (r >> 3) * HIDDEN + u0 + (r & 7);
    wv4[r * 128 + (c4 ^ swz)] = *(const float4*)(w_hh + (size_t)grow * HIDDEN + c4 * 4);
  }
  if (L == 0) {
    for (int idx = tid; idx < 32 * 32; idx += NTH) {
      int r = idx >> 5, c4 = idx & 31, swz = (r >> 2) & 7;
      int grow = (r >> 3) * HIDDEN + u0 + (r & 7);
      wx4[r * 32 + (c4 ^ swz)] = *(const float4*)(w_ih + (size_t)grow * 128 + c4 * 4);
    }
  }
  if (tid < 32) {
    int grow = (tid >> 3) * HIDDEN + u0 + (tid & 7);
    bsum[tid] = b_ih[grow] + b_hh[grow];
  }
  if (tid < 2 * BPG * 8) cst[tid] = 0.0f;

  const int rr = tid & 7;          // row quad
  const int bb = (tid >> 3) & 3;   // batch quad
  const int kc = tid >> 5;         // K chunk 0..7

  const float* wxg[4];             // L1: w_ih rows stream from L2
  if (L == 1) {
#pragma unroll
    for (int j = 0; j < 4; ++j) {
      int r = 4 * rr + j;
      int grow = (r >> 3) * HIDDEN + u0 + (r & 7);
      wxg[j] = w_ih + (size_t)grow * HIDDEN;
    }
  }
  __syncthreads();

  // ---- helpers ----
  auto waitE = [&](int* e, int tgt) {
    if (tgt <= 0) return;
    unsigned long long sp0 = __builtin_amdgcn_s_memrealtime();
    while (ld_ci(e) < tgt) {
      if (__builtin_amdgcn_s_memrealtime() - sp0 > SPIN_LIMIT) break;  // fail, don't hang
      __builtin_amdgcn_s_sleep(1);
    }
    cfence();
  };
  auto issueH = [&](int ci, int t, float* hr) {
    const float* hs = hbc[ci] + (size_t)(t & 1) * (BPG * HIDDEN);
#pragma unroll
    for (int n = 0; n < 32; ++n) {
      int idx = tid + n * NTH;
      int b = idx >> 9, cc = idx & 511;
      hr[n] = ld_cc(hs + b * 512 + cc);
    }
  };
  auto issueX = [&](int ci, int t, float* xr) {
    const int b0 = b0c[ci];
    if (L == 0) {
#pragma unroll
      for (int n = 0; n < 2; ++n) {   // [16][32 f4]
        int idx = tid + n * NTH;
        int b = idx >> 5, c4 = idx & 31;
        float4 v = *(const float4*)(xin + ((size_t)(b0 + b) * TSTEPS + t) * 128 + c4 * 4);
        xr[4 * n + 0] = v.x; xr[4 * n + 1] = v.y; xr[4 * n + 2] = v.z; xr[4 * n + 3] = v.w;
      }
    } else if (SEQMODE == 0) {
#pragma unroll
      for (int n = 0; n < 32; ++n) {
        int idx = tid + n * NTH;
        int b = idx >> 9, cc = idx & 511;
        xr[n] = ld_cc(seqf + ((size_t)(b0 + b) * TSTEPS + t) * HIDDEN + cc);
      }
    } else {
#pragma unroll
      for (int n = 0; n < 16; ++n) {  // [16][256 words]
        int idx = tid + n * NTH;
        int b = idx >> 8, wi = idx & 255;
        unsigned v = ld_cu(sequ + ((size_t)(b0 + b) * TSTEPS + t) * 256 + wi);
        xr[2 * n]     = b2fl((unsigned short)(v & 0xffffu));
        xr[2 * n + 1] = b2fl((unsigned short)(v >> 16));
      }
    }
  };
  auto stageX = [&](int ci, const float* xr) {
    float* st = stf[ci];
    if (L == 0) {
#pragma unroll
      for (int n = 0; n < 2; ++n) {
        int idx = tid + n * NTH;
        int b = idx >> 5, c4 = idx & 31;
        ((float4*)st)[b * 32 + (c4 ^ (b >> 2))] =
            make_float4(xr[4 * n], xr[4 * n + 1], xr[4 * n + 2], xr[4 * n + 3]);
      }
    } else if (SEQMODE == 0) {
#pragma unroll
      for (int n = 0; n < 32; ++n) {
        int idx = tid + n * NTH;
        int b = idx >> 9, cc = idx & 511;
        st[b * 512 + ((((cc >> 2) ^ (b >> 2)) << 2) | (cc & 3))] = xr[n];
      }
    } else {
#pragma unroll
      for (int n = 0; n < 16; ++n) {
        int idx = tid + n * NTH;
        int b = idx >> 8, wi = idx & 255;
        int c0 = wi * 2;
        int base = b * 512 + ((((c0 >> 2) ^ (b >> 2)) << 2) | (c0 & 3));
        st[base]     = xr[2 * n];
        st[base + 1] = xr[2 * n + 1];
      }
    }
  };
  auto stageH = [&](int ci, const float* hr) {
    float* st = stf[ci];
#pragma unroll
    for (int n = 0; n < 32; ++n) {
      int idx = tid + n * NTH;
      int b = idx >> 9, cc = idx & 511;
      st[b * 512 + ((((cc >> 2) ^ (b >> 2)) << 2) | (cc & 3))] = hr[n];
    }
  };
  auto xpart = [&](int ci, float acc[4][4]) {
    float4* st4 = (float4*)stf[ci];
    if (L == 0) {
#pragma unroll
      for (int kk = 0; kk < 4; ++kk) {
        const int k4 = kc * 4 + kk;
        float4 wq[4], xq[4];
#pragma unroll
        for (int j = 0; j < 4; ++j) wq[j] = wx4[(4 * rr + j) * 32 + (k4 ^ rr)];
#pragma unroll
        for (int i = 0; i < 4; ++i) xq[i] = st4[(4 * bb + i) * 32 + (k4 ^ bb)];
#pragma unroll
        for (int j = 0; j < 4; ++j)
#pragma unroll
          for (int i = 0; i < 4; ++i) fma4(acc[j][i], wq[j], xq[i]);
      }
    } else {
#pragma unroll 2
      for (int kk = 0; kk < 16; ++kk) {
        const int k4 = kc * 16 + kk;
        float4 wq[4], xq[4];
#pragma unroll
        for (int j = 0; j < 4; ++j) wq[j] = *(const float4*)(wxg[j] + k4 * 4);
#pragma unroll
        for (int i = 0; i < 4; ++i) xq[i] = st4[(4 * bb + i) * 128 + (k4 ^ bb)];
#pragma unroll
        for (int j = 0; j < 4; ++j)
#pragma unroll
          for (int i = 0; i < 4; ++i) fma4(acc[j][i], wq[j], xq[i]);
      }
    }
  };
  auto hpart = [&](int ci, float acc[4][4]) {
    float4* st4 = (float4*)stf[ci];
#pragma unroll 4
    for (int kk = 0; kk < 16; ++kk) {
      const int k4 = kc * 16 + kk;
      float4 wq[4], hq[4];
#pragma unroll
      for (int j = 0; j < 4; ++j) wq[j] = wv4[(4 * rr + j) * 128 + (k4 ^ rr)];
#pragma unroll
      for (int i = 0; i < 4; ++i) hq[i] = st4[(4 * bb + i) * 128 + (k4 ^ bb)];
#pragma unroll
      for (int j = 0; j < 4; ++j)
#pragma unroll
        for (int i = 0; i < 4; ++i) fma4(acc[j][i], wq[j], hq[i]);
    }
  };
  auto finish = [&](int ci, int t, float acc[4][4]) {
    float* red = stf[ci];                 // reduction overlays the stage buffer
    __syncthreads();                      // h-part reads done before overlay
#pragma unroll
    for (int j = 0; j < 4; ++j)
#pragma unroll
      for (int i = 0; i < 4; ++i)
        red[kc * 512 + (4 * rr + j) * 16 + 4 * bb + i] = acc[j][i];
    __syncthreads();
    {
      const int a0 = tid, a1 = tid + 256;
      float s0v = bsum[a0 >> 4], s1v = bsum[a1 >> 4];
#pragma unroll
      for (int k2 = 0; k2 < 8; ++k2) { s0v += red[k2 * 512 + a0]; s1v += red[k2 * 512 + a1]; }
      red[a0] = s0v; red[a1] = s1v;
    }
    __syncthreads();
    if (tid < 128) {
      const int lu = tid & 7, bl = tid >> 3;
      float gi = red[(0  + lu) * 16 + bl];
      float gf = red[(8  + lu) * 16 + bl];
      float gg = red[(16 + lu) * 16 + bl];
      float go = red[(24 + lu) * 16 + bl];
      float iv = sigm(gi), fv = sigm(gf), gv = tanh_fast(gg), ov = sigm(go);
      float* cc = cst + ci * 128 + tid;
      float c = fv * (*cc) + iv * gv;
      *cc = c;
      float hn = ov * tanh_fast(c);
      st_cc(hbc[ci] + (size_t)((t + 1) & 1) * (BPG * HIDDEN) + bl * 512 + u0 + lu, hn);
      if (L == 0) {
        if (SEQMODE == 0) {
          st_cc(seqf + ((size_t)(b0c[ci] + bl) * TSTEPS + t) * HIDDEN + u0 + lu, hn);
        } else {
          float other = __shfl_xor(hn, 1);
          if ((lu & 1) == 0) {
            bf16 lo = __float2bfloat16(hn), hi = __float2bfloat16(other);
            unsigned pv = (unsigned)(*(unsigned short*)&lo) |
                          ((unsigned)(*(unsigned short*)&hi) << 16);
            st_cu(sequ + ((size_t)(b0c[ci] + bl) * TSTEPS + t) * 256 + ((u0 + lu) >> 1), pv);
          }
        }
      } else if (t == TSTEPS - 1) {
        st_cc(fin + (size_t)(b0c[ci] + bl) * HIDDEN + u0 + lu, hn);
      }
    }
    __syncthreads();                      // drain h stores before flag
    if (tid == 0) st_ci(fl[ci] + w, t + 1);
    cfence();
    if (w == ci && tid < 64) {            // per-chain gatherer wg
      unsigned long long sp0 = __builtin_amdgcn_s_memrealtime();
      while (true) {
        int v = ld_ci(fl[ci] + tid);
        if (__all(v >= t + 1)) break;
        if (__builtin_amdgcn_s_memrealtime() - sp0 > SPIN_LIMIT) break;
        __builtin_amdgcn_s_sleep(1);
      }
      if (tid == 0) st_ci(ep[ci], t + 1);
    }
  };

  // ---- prologue: issue chain A step 0 ----
  float hrA[32], hrB[32], xrA[32], xrB[32];
  if (L == 1) waitE(ep0[0], 1);
  issueX(0, 0, xrA);
  issueH(0, 0, hrA);

  for (int t = 0; t < TSTEPS; ++t) {
    float acc[4][4];

    // ================= phase A (chain cA, step t) =================
    stageX(0, xrA);
    __syncthreads();
#pragma unroll
    for (int j = 0; j < 4; ++j)
#pragma unroll
      for (int i = 0; i < 4; ++i) acc[j][i] = 0.0f;
    xpart(0, acc);
    {   // wait/issue chain B (latency hides under A's h-part)
      waitE(ep[1], t);
      if (L == 1) waitE(ep0[1], t + 1);
      issueX(1, t, xrB);
      issueH(1, t, hrB);
    }
    __syncthreads();          // x reads done before h overwrites stage
    stageH(0, hrA);
    __syncthreads();
    hpart(0, acc);
    finish(0, t, acc);

    // ================= phase B (chain cB, step t) =================
    stageX(1, xrB);
    __syncthreads();
#pragma unroll
    for (int j = 0; j < 4; ++j)
#pragma unroll
      for (int i = 0; i < 4; ++i) acc[j][i] = 0.0f;
    xpart(1, acc);
    if (t < TSTEPS - 1) {     // wait/issue chain A step t+1
      waitE(ep[0], t + 1);
      if (L == 1) waitE(ep0[0], t + 2);
      issueX(0, t + 1, xrA);
      issueH(0, t + 1, hrA);
    }
    __syncthreads();
    stageH(1, hrB);
    __syncthreads();
    hpart(1, acc);
    finish(1, t, acc);
  }
}

// ---------------------------------------------------------------------------
// FC: out[b][o] = dot(fin[b], fc_w[o]) + fc_b[o].  grid 8, block 256.
// ---------------------------------------------------------------------------
__global__ __launch_bounds__(NTH, 1)
void fc_kernel(const float* __restrict__ h2, const float* __restrict__ fcw,
               const float* __restrict__ fcb, float* __restrict__ out)
{
  extern __shared__ float lds[];
  float4* fw4 = (float4*)lds;          // [64][128] swizzled
  float4* h24 = fw4 + 64 * 128;        // [8][128]
  const int tid = threadIdx.x;
  const int bq  = blockIdx.x;

  for (int idx = tid; idx < 64 * 128; idx += NTH) {
    int o = idx >> 7, c4 = idx & 127;
    fw4[o * 128 + (c4 ^ (o & 7))] = *(const float4*)(fcw + (size_t)o * HIDDEN + c4 * 4);
  }
  for (int idx = tid; idx < 8 * 128; idx += NTH) {
    int b = idx >> 7, c4 = idx & 127;
    h24[b * 128 + c4] = *(const float4*)(h2 + (size_t)(bq * 8 + b) * HIDDEN + c4 * 4);
  }
  __syncthreads();

  const int o = tid & 63, bs = tid >> 6;
  float a0 = 0.f, a1 = 0.f;
  for (int c4 = 0; c4 < 128; ++c4) {
    float4 wv = fw4[o * 128 + (c4 ^ (o & 7))];
    float4 h0 = h24[(2 * bs) * 128 + c4];
    float4 h1 = h24[(2 * bs + 1) * 128 + c4];
    fma4(a0, wv, h0);
    fma4(a1, wv, h1);
  }
  const float bo = fcb[o];
  out[(size_t)(bq * 8 + 2 * bs) * 64 + o]     = a0 + bo;
  out[(size_t)(bq * 8 + 2 * bs + 1) * 64 + o] = a1 + bo;
}

__global__ void init_ws(float* hbufs, int* bars)
{
  int i = blockIdx.x * blockDim.x + threadIdx.x;
  if (i < 2 * 4 * 2 * BPG * HIDDEN) hbufs[i] = 0.f;   // 131072 floats
  if (i < 1024) bars[i] = 0;
}

// ---------------------------------------------------------------------------
extern "C" void kernel_launch(void* const* d_in, const int* in_sizes, int n_in,
                              void* d_out, int out_size, void* d_ws, size_t ws_size,
                              hipStream_t stream)
{
  const float* x    = (const float*)d_in[0];
  const float* wih0 = (const float*)d_in[1];
  const float* whh0 = (const float*)d_in[2];
  const float* bih0 = (const float*)d_in[3];
  const float* bhh0 = (const float*)d_in[4];
  const float* wih1 = (const float*)d_in[5];
  const float* whh1 = (const float*)d_in[6];
  const float* bih1 = (const float*)d_in[7];
  const float* bhh1 = (const float*)d_in[8];
  const float* fcw  = (const float*)d_in[9];
  const float* fcb  = (const float*)d_in[10];
  float* out = (float*)d_out;

  // ws layout (floats): bars 1024i | hbufs 131072 | fin 32768 | seq
  float* wsf   = (float*)d_ws;
  int*   bars  = (int*)d_ws;
  float* hbufs = wsf + 1024;
  float* fin   = hbufs + 2 * 4 * 2 * BPG * HIDDEN;
  void*  seqv  = (void*)(fin + BATCH * HIDDEN);

  const size_t head_bytes = (size_t)(1024 + 131072 + 32768) * 4;
  const size_t seq_f32    = (size_t)BATCH * TSTEPS * HIDDEN * 4;
  const bool f32seq = ws_size >= head_bytes + seq_f32;

  const size_t ldsF  = (size_t)(32 * 128 + 32 * 32) * 16 +
                       (size_t)(2 * BPG * HIDDEN + 32 + 256) * 4;   // 148,608 B
  const size_t ldsfc = (size_t)(64 * 128 + 8 * 128) * 16;

  hipLaunchKernelGGL(init_ws, dim3(512), dim3(256), 0, stream, hbufs, bars);

  if (f32seq) {
    auto* k = lstm_fused<0>;
    hipFuncSetAttribute((const void*)k, hipFuncAttributeMaxDynamicSharedMemorySize, (int)ldsF);
    void* args[] = { (void*)&x,
                     (void*)&wih0, (void*)&whh0, (void*)&bih0, (void*)&bhh0,
                     (void*)&wih1, (void*)&whh1, (void*)&bih1, (void*)&bhh1,
                     (void*)&hbufs, (void*)&seqv, (void*)&fin, (void*)&bars };
    if (hipLaunchCooperativeKernel((const void*)k, dim3(256), dim3(NTH), args,
                                   (unsigned)ldsF, stream) != hipSuccess) {
      lstm_fused<0><<<dim3(256), dim3(NTH), ldsF, stream>>>(
          x, wih0, whh0, bih0, bhh0, wih1, whh1, bih1, bhh1, hbufs, seqv, fin, bars);
    }
  } else {
    auto* k = lstm_fused<1>;
    hipFuncSetAttribute((const void*)k, hipFuncAttributeMaxDynamicSharedMemorySize, (int)ldsF);
    void* args[] = { (void*)&x,
                     (void*)&wih0, (void*)&whh0, (void*)&bih0, (void*)&bhh0,
                     (void*)&wih1, (void*)&whh1, (void*)&bih1, (void*)&bhh1,
                     (void*)&hbufs, (void*)&seqv, (void*)&fin, (void*)&bars };
    if (hipLaunchCooperativeKernel((const void*)k, dim3(256), dim3(NTH), args,
                                   (unsigned)ldsF, stream) != hipSuccess) {
      lstm_fused<1><<<dim3(256), dim3(NTH), ldsF, stream>>>(
          x, wih0, whh0, bih0, bhh0, wih1, whh1, bih1, bhh1, hbufs, seqv, fin, bars);
    }
  }

  hipFuncSetAttribute((const void*)fc_kernel, hipFuncAttributeMaxDynamicSharedMemorySize, (int)ldsfc);
  hipLaunchKernelGGL(fc_kernel, dim3(8), dim3(NTH), ldsfc, stream, fin, fcw, fcb, out);
}